// Round 10
// baseline (661.809 us; speedup 1.0000x reference)
//
#include <hip/hip_runtime.h>
#include <math.h>

#define NN 16384      // B*N total nodes
#define NPB 4096      // nodes per batch
#define KCAP 128      // survivor capacity per query (expected ~20)

__device__ __forceinline__ float gelu_f(float v){
  return 0.5f*v*(1.0f+erff(v*0.70710678118654752440f));
}

// monotone float->uint map: order-preserving for all finite values
__device__ __forceinline__ unsigned fmap(float d2){
  unsigned u = __float_as_uint(d2);
  return u ^ ((unsigned)((int)u >> 31) | 0x80000000u);
}

// distance key: one canonical inlined form so all uses produce bit-identical values
__device__ __forceinline__ unsigned dkey(const float4 qa, const float4 qb, const float sqn,
                                         const float4 a, const float4 b){
  const float dot = qa.x*a.x + qa.y*a.y + qa.z*a.z + qa.w*a.w + qb.x*b.x + qb.y*b.y;
  const float d2 = sqn + b.z - 2.0f*dot;
  return fmap(d2);
}

// ascending-by-lane bitonic sort of one u64 per lane across the 64-lane wave
__device__ __forceinline__ unsigned long long bsort64(unsigned long long v, int lane){
#pragma unroll
  for (int k=2;k<=64;k<<=1){
#pragma unroll
    for (int j=k>>1;j>0;j>>=1){
      const unsigned long long o = __shfl_xor(v, j);
      const bool keepMin = ((lane & k) == 0) == ((lane & j) == 0);
      const unsigned long long mn = v < o ? v : o;
      const unsigned long long mx = v < o ? o : v;
      v = keepMin ? mn : mx;
    }
  }
  return v;
}

// ascending-by-lane bitonic sort of one u32 per lane
__device__ __forceinline__ unsigned bsort32(unsigned v, int lane){
#pragma unroll
  for (int k=2;k<=64;k<<=1){
#pragma unroll
    for (int j=k>>1;j>0;j>>=1){
      const unsigned o = __shfl_xor(v, j);
      const bool keepMin = ((lane & k) == 0) == ((lane & j) == 0);
      const unsigned mn = v < o ? v : o;
      const unsigned mx = v < o ? o : v;
      v = keepMin ? mn : mx;
    }
  }
  return v;
}

// ---------------- pack: x[NN,6] -> PA[NN]={x0..x3}, PB[NN]={x4,x5,sq,0} ----------------
__global__ __launch_bounds__(256) void pack_k(const float* __restrict__ x,
                                              float4* __restrict__ PA, float4* __restrict__ PB){
  const int n = blockIdx.x*256 + threadIdx.x;
  const float* xr = x + (size_t)n*6;
  const float x0=xr[0],x1=xr[1],x2=xr[2],x3=xr[3],x4=xr[4],x5=xr[5];
  const float sq = x0*x0+x1*x1+x2*x2+x3*x3+x4*x4+x5*x5;
  PA[n] = make_float4(x0,x1,x2,x3);
  PB[n] = make_float4(x4,x5,sq,0.f);
}

// ---------------- kNN v9b: batch-resident dynamic LDS (128 KB, staged ONCE, one barrier),
//                  16 waves/block, 2 queries per wave, 16-bit packed keys in regs,
//                  exact tail per query (macro takes query vecs as ARGUMENTS) ----------------
#define KNN_TAIL(KP, MINU, QA, QB, SQN, NOUT)                                      \
  {                                                                                \
    unsigned T = bsort32((MINU), lane);                                            \
    T = __shfl(T, 15);                                                             \
    const unsigned T16 = T >> 16;                                                  \
    int cnt = 0;                                                                   \
    _Pragma("unroll")                                                              \
    for (int q=0; q<64; ++q){                                                      \
      const unsigned k16 = ((KP)[q>>1] >> ((q&1)*16)) & 0xFFFFu;                   \
      const bool p = k16 <= T16;                                                   \
      const unsigned long long bb = __ballot(p);                                   \
      if (p){                                                                      \
        const int pos = cnt + (int)__popcll(bb & ((1ull << lane) - 1ull));         \
        if (pos < KCAP) sslot[w][pos] = (unsigned)(q*64 + lane);                   \
      }                                                                            \
      cnt += (int)__popcll(bb);                                                    \
    }                                                                              \
    if (cnt > KCAP) cnt = KCAP;                                                    \
    for (int i=lane; i<cnt; i+=64){                                                \
      const int slot = (int)sslot[w][i];                                           \
      skey[w][i] = dkey((QA), (QB), (SQN), A4[slot], B4[slot]);                    \
    }                                                                              \
    unsigned long long vbest;                                                      \
    {                                                                              \
      unsigned long long v = ~0ull;                                                \
      if (lane < cnt) v = ((unsigned long long)skey[w][lane] << 32) | sslot[w][lane]; \
      vbest = bsort64(v, lane);                                                    \
    }                                                                              \
    for (int c=1; c*64 < cnt; ++c){                                                \
      const int i = c*64 + lane;                                                   \
      unsigned long long v = ~0ull;                                                \
      if (i < cnt) v = ((unsigned long long)skey[w][i] << 32) | sslot[w][i];       \
      v = bsort64(v, lane);                                                        \
      const unsigned long long r = __shfl(v, 63-lane);                             \
      vbest = vbest < r ? vbest : r;                                               \
      _Pragma("unroll")                                                            \
      for (int j=32;j>0;j>>=1){                                                    \
        const unsigned long long o = __shfl_xor(vbest, j);                         \
        const bool keepMin = (lane & j) == 0;                                      \
        const unsigned long long mn = vbest < o ? vbest : o;                       \
        const unsigned long long mx = vbest < o ? o : vbest;                       \
        vbest = keepMin ? mn : mx;                                                 \
      }                                                                            \
    }                                                                              \
    if (lane < 16) nbr[(NOUT)*16 + lane] = base + (int)(vbest & 0xFFFFFFFFull);    \
  }

__global__ __launch_bounds__(1024, 1) void knn_k(const float4* __restrict__ PA,
                                                 const float4* __restrict__ PB,
                                                 int* __restrict__ nbr){
  extern __shared__ float4 dynls[];
  float4* A4 = dynls;          // [4096]
  float4* B4 = dynls + NPB;    // [4096]
  __shared__ unsigned skey[16][KCAP];
  __shared__ unsigned sslot[16][KCAP];
  const int t = threadIdx.x, w = t >> 6, lane = t & 63;
  const int q0g = blockIdx.x*32 + 2*w;      // this wave's two queries
  const int base = q0g & ~(NPB-1);

  // stage the whole batch once
  for (int i=t; i<NPB; i+=1024){
    A4[i] = PA[base+i];
    B4[i] = PB[base+i];
  }
  __syncthreads();

  const float4 qa0 = PA[q0g],   qb0 = PB[q0g];
  const float4 qa1 = PA[q0g+1], qb1 = PB[q0g+1];
  const float sqn0 = qb0.z, sqn1 = qb1.z;
  const int self0 = q0g - base, self1 = self0 + 1;

  unsigned kp0[32], kp1[32];
  unsigned minu0 = 0xFFFFFFFFu, minu1 = 0xFFFFFFFFu;
  unsigned lo0 = 0, lo1 = 0;
#pragma unroll
  for (int it=0; it<64; ++it){
    const int s = it*64 + lane;
    const float4 a = A4[s];
    const float4 b = B4[s];
    unsigned u0 = dkey(qa0, qb0, sqn0, a, b);
    unsigned u1 = dkey(qa1, qb1, sqn1, a, b);
    if (s == self0) u0 = 0xFFFFFFFFu;
    if (s == self1) u1 = 0xFFFFFFFFu;
    minu0 = u0 < minu0 ? u0 : minu0;
    minu1 = u1 < minu1 ? u1 : minu1;
    if ((it & 1) == 0){ lo0 = u0 >> 16; lo1 = u1 >> 16; }
    else { kp0[it>>1] = lo0 | (u0 & 0xFFFF0000u); kp1[it>>1] = lo1 | (u1 & 0xFFFF0000u); }
  }

  KNN_TAIL(kp0, minu0, qa0, qb0, sqn0, q0g)
  KNN_TAIL(kp1, minu1, qa1, qb1, sqn1, q0g+1)
}

// ---------------- layer-1 GEMM + fused attention logits:
//                  x[NN,6] @ W1[6,256]; one wave per node -> als/ald via 16-lane reduce ----
__global__ __launch_bounds__(256) void gemm_in6(const float* __restrict__ x, const float* __restrict__ W,
                                                const float* __restrict__ asrc, const float* __restrict__ adst,
                                                float* __restrict__ h,
                                                float* __restrict__ als, float* __restrict__ ald){
  const int t = blockIdx.x*256 + threadIdx.x;  // over NN*64
  const int n = t >> 6, cg = t & 63;
  const float* xr = x + n*6;
  float xv[6];
#pragma unroll
  for (int d=0; d<6; d++) xv[d] = xr[d];
  float4 acc = make_float4(0.f,0.f,0.f,0.f);
#pragma unroll
  for (int d=0; d<6; d++){
    const float4 wv = *(const float4*)(W + d*256 + cg*4);
    acc.x += xv[d]*wv.x; acc.y += xv[d]*wv.y; acc.z += xv[d]*wv.z; acc.w += xv[d]*wv.w;
  }
  *(float4*)(h + n*256 + cg*4) = acc;

  // fused attention logits: head = cg>>4, 4 cols per lane, 16-lane tree reduce
  const int head = cg >> 4;
  const float4 av = *(const float4*)(asrc + head*64 + (cg&15)*4);
  const float4 dv = *(const float4*)(adst + head*64 + (cg&15)*4);
  float s = acc.x*av.x + acc.y*av.y + acc.z*av.z + acc.w*av.w;
  float d = acc.x*dv.x + acc.y*dv.y + acc.z*dv.z + acc.w*dv.w;
#pragma unroll
  for (int off=1; off<16; off<<=1){
    s += __shfl_xor(s, off);
    d += __shfl_xor(d, off);
  }
  if ((cg & 15) == 0){
    als[n*4 + head] = s;
    ald[n*4 + head] = d;
  }
}

// ---------------- attention logits: als/ald [NN,HEADS] ----------------
template<int HEADS, int C>
__global__ __launch_bounds__(256) void al_k(const float* __restrict__ h, const float* __restrict__ asrc,
                                            const float* __restrict__ adst, float* __restrict__ als,
                                            float* __restrict__ ald){
  const int t = blockIdx.x*256 + threadIdx.x;  // over NN*HEADS
  const int n = t / HEADS, hd = t % HEADS;
  const float* hp = h + (n*HEADS + hd)*C;
  const float* ap = asrc + hd*C;
  const float* dp = adst + hd*C;
  float s=0.f, d=0.f;
#pragma unroll 4
  for (int c=0;c<C;c+=4){
    const float4 v = *(const float4*)(hp+c);
    const float4 a = *(const float4*)(ap+c);
    const float4 b = *(const float4*)(dp+c);
    s += v.x*a.x + v.y*a.y + v.z*a.z + v.w*a.w;
    d += v.x*b.x + v.y*b.y + v.z*b.z + v.w*b.w;
  }
  als[t] = s; ald[t] = d;
}

// ---------------- GAT aggregation: one wave per node, 17-way softmax gather;
//                  RES fuses the x@res_W + res_b residual (layer 3) ----------------
template<int HEADS, int C, bool RES>
__global__ __launch_bounds__(256) void agg_k(const float* __restrict__ h, const float* __restrict__ als,
                                             const float* __restrict__ ald, const int* __restrict__ nbr,
                                             const float* __restrict__ bias, float* __restrict__ out,
                                             const float* __restrict__ xin, const float* __restrict__ rW,
                                             const float* __restrict__ rb){
  constexpr int CT = HEADS*C;
  constexpr int F  = CT/64;
  const int w = threadIdx.x >> 6, lane = threadIdx.x & 63;
  const int n = blockIdx.x*4 + w;
  const int head = (lane*F)/C;
  const int col  = lane*F;
  const int nb = nbr[n*16 + (lane & 15)];
  const float aldn = ald[n*HEADS + head];
  float e[17];
#pragma unroll
  for (int j=0;j<17;j++){
    const int sj = (j<16) ? __shfl(nb, j) : n;
    const float v = als[sj*HEADS + head] + aldn;
    e[j] = v > 0.f ? v : 0.2f*v;
  }
  float mx = e[0];
#pragma unroll
  for (int j=1;j<17;j++) mx = fmaxf(mx, e[j]);
  float den = 0.f;
#pragma unroll
  for (int j=0;j<17;j++){ e[j] = expf(e[j]-mx); den += e[j]; }
  float acc[F];
#pragma unroll
  for (int f=0;f<F;f++) acc[f]=0.f;
#pragma unroll
  for (int j=0;j<17;j++){
    const int sj = (j<16) ? __shfl(nb, j) : n;
    const float* hp = h + sj*CT + col;
    if constexpr (F==4){
      const float4 v = *(const float4*)hp;
      acc[0] += e[j]*v.x; acc[1] += e[j]*v.y; acc[2] += e[j]*v.z; acc[3] += e[j]*v.w;
    } else {
      const float2 v = *(const float2*)hp;
      acc[0] += e[j]*v.x; acc[1] += e[j]*v.y;
    }
  }
  const float inv = 1.f/den;
  if constexpr (F==4){
    float4 o;
    o.x = gelu_f(acc[0]*inv + bias[col+0]);
    o.y = gelu_f(acc[1]*inv + bias[col+1]);
    o.z = gelu_f(acc[2]*inv + bias[col+2]);
    o.w = gelu_f(acc[3]*inv + bias[col+3]);
    *(float4*)(out + n*CT + col) = o;
  } else {
    float2 o;
    o.x = gelu_f(acc[0]*inv + bias[col+0]);
    o.y = gelu_f(acc[1]*inv + bias[col+1]);
    if constexpr (RES){
      const float* xr = xin + (size_t)n*6;
      float r0 = rb[col+0], r1 = rb[col+1];
#pragma unroll
      for (int d=0; d<6; d++){
        const float xv = xr[d];
        r0 += xv*rW[d*128 + col+0];
        r1 += xv*rW[d*128 + col+1];
      }
      o.x += r0; o.y += r1;
    }
    *(float2*)(out + n*CT + col) = o;
  }
}

// ---------------- generic fp32 tiled GEMM: [M,KC] @ [KC,NC], BM=128 BN=64 BK=32 ----------------
template<int KC, int NC, bool BIAS, bool GELU>
__global__ __launch_bounds__(256) void gemm_k(const float* __restrict__ A, const float* __restrict__ B,
                                              const float* __restrict__ bias, float* __restrict__ C){
  __shared__ float Ast[32][132];   // A chunk transposed: Ast[k][row]
  __shared__ float Bs[32][64];
  const int t  = threadIdx.x;
  const int r0 = blockIdx.x*128;
  const int c0 = blockIdx.y*64;
  const int ty = t >> 4, tx = t & 15;
  const int ar = t >> 1, ac = (t & 1)*16;
  const int br = t >> 3, bc = (t & 7)*8;
  float acc[8][4];
#pragma unroll
  for (int i=0;i<8;i++)
#pragma unroll
    for (int j=0;j<4;j++) acc[i][j] = 0.f;

#pragma unroll 1
  for (int kc=0; kc<KC; kc+=32){
    const float* Ap = A + (size_t)(r0+ar)*KC + kc + ac;
    float4 av[4];
#pragma unroll
    for (int u=0;u<4;u++) av[u] = *(const float4*)(Ap + u*4);
#pragma unroll
    for (int u=0;u<4;u++){
      Ast[ac+u*4+0][ar] = av[u].x;
      Ast[ac+u*4+1][ar] = av[u].y;
      Ast[ac+u*4+2][ar] = av[u].z;
      Ast[ac+u*4+3][ar] = av[u].w;
    }
    const float* Bp = B + (size_t)(kc+br)*NC + c0 + bc;
    *(float4*)&Bs[br][bc]   = *(const float4*)Bp;
    *(float4*)&Bs[br][bc+4] = *(const float4*)(Bp+4);
    __syncthreads();
#pragma unroll
    for (int k=0;k<32;k++){
      const float4 a0 = *(const float4*)&Ast[k][ty*8];
      const float4 a1 = *(const float4*)&Ast[k][ty*8+4];
      const float4 bv = *(const float4*)&Bs[k][tx*4];
      const float avr[8] = {a0.x,a0.y,a0.z,a0.w,a1.x,a1.y,a1.z,a1.w};
      const float bbr[4] = {bv.x,bv.y,bv.z,bv.w};
#pragma unroll
      for (int i=0;i<8;i++)
#pragma unroll
        for (int j=0;j<4;j++)
          acc[i][j] += avr[i]*bbr[j];
    }
    __syncthreads();
  }
#pragma unroll
  for (int i=0;i<8;i++){
    const int r = r0 + ty*8 + i;
    float vv[4];
#pragma unroll
    for (int j=0;j<4;j++){
      float v = acc[i][j];
      if constexpr (BIAS) v += bias[c0 + tx*4 + j];
      if constexpr (GELU) v = gelu_f(v);
      vv[j] = v;
    }
    *(float4*)(C + (size_t)r*NC + c0 + tx*4) = make_float4(vv[0],vv[1],vv[2],vv[3]);
  }
}

// ---------------- final tiny GEMM: [NN,64] @ [64,6] + b ----------------
__global__ __launch_bounds__(256) void m3_k(const float* __restrict__ A, const float* __restrict__ W,
                                            const float* __restrict__ bias, float* __restrict__ out){
  __shared__ float Wl[64*6];
  __shared__ float bl[6];
  const int t = threadIdx.x;
  for (int i=t; i<384; i+=256) Wl[i] = W[i];
  if (t < 6) bl[t] = bias[t];
  __syncthreads();
  const int n = blockIdx.x*256 + t;
  const float* ap = A + n*64;
  float acc[6] = {0.f,0.f,0.f,0.f,0.f,0.f};
  for (int k=0;k<64;k+=4){
    const float4 v = *(const float4*)(ap+k);
    const float vr[4] = {v.x,v.y,v.z,v.w};
#pragma unroll
    for (int u=0;u<4;u++)
#pragma unroll
      for (int j=0;j<6;j++)
        acc[j] += vr[u]*Wl[(k+u)*6+j];
  }
#pragma unroll
  for (int j=0;j<6;j++) out[n*6+j] = acc[j] + bl[j];
}

extern "C" void kernel_launch(void* const* d_in, const int* in_sizes, int n_in,
                              void* d_out, int out_size, void* d_ws, size_t ws_size,
                              hipStream_t stream){
  (void)in_sizes; (void)n_in; (void)out_size; (void)ws_size;
  const float* x      = (const float*)d_in[0];
  const float* W1     = (const float*)d_in[1];
  const float* a_src1 = (const float*)d_in[2];
  const float* a_dst1 = (const float*)d_in[3];
  const float* b1     = (const float*)d_in[4];
  const float* W2     = (const float*)d_in[5];
  const float* a_src2 = (const float*)d_in[6];
  const float* a_dst2 = (const float*)d_in[7];
  const float* b2     = (const float*)d_in[8];
  const float* W3     = (const float*)d_in[9];
  const float* a_src3 = (const float*)d_in[10];
  const float* a_dst3 = (const float*)d_in[11];
  const float* b3     = (const float*)d_in[12];
  const float* res_W  = (const float*)d_in[13];
  const float* res_b  = (const float*)d_in[14];
  const float* m1_W   = (const float*)d_in[15];
  const float* m1_b   = (const float*)d_in[16];
  const float* m2_W   = (const float*)d_in[17];
  const float* m2_b   = (const float*)d_in[18];
  const float* m3_W   = (const float*)d_in[19];
  const float* m3_b   = (const float*)d_in[20];
  float* out = (float*)d_out;

  char* wsb = (char*)d_ws;
  int*   nbr = (int*)wsb;                                   // 1 MB
  float* H   = (float*)(wsb + (1u<<20));                    // 16 MB
  float* Y   = (float*)(wsb + (1u<<20) + (16u<<20));        // 16 MB
  float* ALS = (float*)(wsb + (1u<<20) + (32u<<20));        // 256 KB
  float* ALD = ALS + NN*4;                                  // 256 KB
  float4* PA = (float4*)(wsb + (1u<<20) + (32u<<20) + (512u<<10)); // 256 KB
  float4* PB = PA + NN;                                            // 256 KB

  static int lds_set = 0;
  if (!lds_set){
    (void)hipFuncSetAttribute((const void*)knn_k,
                              hipFuncAttributeMaxDynamicSharedMemorySize, NPB*32);
    lds_set = 1;
  }

  pack_k<<<NN/256, 256, 0, stream>>>(x, PA, PB);
  knn_k<<<NN/32, 1024, NPB*32, stream>>>(PA, PB, nbr);

  // GAT layer 1: 6 -> 4x64 (attention logits fused into the GEMM)
  gemm_in6<<<NN/4, 256, 0, stream>>>(x, W1, a_src1, a_dst1, H, ALS, ALD);
  agg_k<4,64,false><<<NN/4, 256, 0, stream>>>(H, ALS, ALD, nbr, b1, Y, nullptr, nullptr, nullptr);

  // GAT layer 2: 256 -> 4x64
  gemm_k<256,256,false,false><<<dim3(NN/128, 4), 256, 0, stream>>>(Y, W2, nullptr, H);
  al_k<4,64><<<NN*4/256, 256, 0, stream>>>(H, a_src2, a_dst2, ALS, ALD);
  agg_k<4,64,false><<<NN/4, 256, 0, stream>>>(H, ALS, ALD, nbr, b2, Y, nullptr, nullptr, nullptr);

  // GAT layer 3: 256 -> 1x128, residual fused
  gemm_k<256,128,false,false><<<dim3(NN/128, 2), 256, 0, stream>>>(Y, W3, nullptr, H);
  al_k<1,128><<<NN/256, 256, 0, stream>>>(H, a_src3, a_dst3, ALS, ALD);
  agg_k<1,128,true><<<NN/4, 256, 0, stream>>>(H, ALS, ALD, nbr, b3, Y, x, res_W, res_b);

  // MLP
  gemm_k<128,128,true,true><<<dim3(NN/128, 2), 256, 0, stream>>>(Y, m1_W, m1_b, H);
  gemm_k<128,64,true,true><<<dim3(NN/128, 1), 256, 0, stream>>>(H, m2_W, m2_b, Y);
  m3_k<<<NN/256, 256, 0, stream>>>(Y, m3_W, m3_b, out);
}

// Round 11
// 218.348 us; speedup vs baseline: 3.0310x; 3.0310x over previous
//
#include <hip/hip_runtime.h>
#include <math.h>

#define NN 16384      // B*N total nodes
#define NPB 4096      // nodes per batch
#define KCAP 128      // survivor capacity per query (expected ~20)
#define TS 512        // kNN candidate tile size (LDS 20480 B)

typedef __attribute__((ext_vector_type(8))) short short8v;
typedef __attribute__((ext_vector_type(4))) float float4v;

__device__ __forceinline__ float gelu_f(float v){
  return 0.5f*v*(1.0f+erff(v*0.70710678118654752440f));
}

// f32 -> bf16 bits, round-to-nearest-even
__device__ __forceinline__ unsigned short f2bf(float v){
  union{float f; unsigned u;} c; c.f = v;
  const unsigned r = c.u + 0x7FFFu + ((c.u >> 16) & 1u);
  return (unsigned short)(r >> 16);
}
__device__ __forceinline__ float bf2f(unsigned short b){
  return __uint_as_float(((unsigned)b) << 16);
}

// monotone float->uint map: order-preserving for all finite values
__device__ __forceinline__ unsigned fmap(float d2){
  unsigned u = __float_as_uint(d2);
  return u ^ ((unsigned)((int)u >> 31) | 0x80000000u);
}

// distance key: one canonical inlined form so all uses produce bit-identical values
__device__ __forceinline__ unsigned dkey(const float4 qa, const float4 qb, const float sqn,
                                         const float4 a, const float4 b){
  const float dot = qa.x*a.x + qa.y*a.y + qa.z*a.z + qa.w*a.w + qb.x*b.x + qb.y*b.y;
  const float d2 = sqn + b.z - 2.0f*dot;
  return fmap(d2);
}

// ascending-by-lane bitonic sort of one u64 per lane across the 64-lane wave
__device__ __forceinline__ unsigned long long bsort64(unsigned long long v, int lane){
#pragma unroll
  for (int k=2;k<=64;k<<=1){
#pragma unroll
    for (int j=k>>1;j>0;j>>=1){
      const unsigned long long o = __shfl_xor(v, j);
      const bool keepMin = ((lane & k) == 0) == ((lane & j) == 0);
      const unsigned long long mn = v < o ? v : o;
      const unsigned long long mx = v < o ? o : v;
      v = keepMin ? mn : mx;
    }
  }
  return v;
}

// ascending-by-lane bitonic sort of one u32 per lane
__device__ __forceinline__ unsigned bsort32(unsigned v, int lane){
#pragma unroll
  for (int k=2;k<=64;k<<=1){
#pragma unroll
    for (int j=k>>1;j>0;j>>=1){
      const unsigned o = __shfl_xor(v, j);
      const bool keepMin = ((lane & k) == 0) == ((lane & j) == 0);
      const unsigned mn = v < o ? v : o;
      const unsigned mx = v < o ? o : v;
      v = keepMin ? mn : mx;
    }
  }
  return v;
}

// ---------------- pack: x[NN,6] -> PA[NN]={x0..x3}, PB[NN]={x4,x5,sq,0} ----------------
__global__ __launch_bounds__(256) void pack_k(const float* __restrict__ x,
                                              float4* __restrict__ PA, float4* __restrict__ PB){
  const int n = blockIdx.x*256 + threadIdx.x;
  const float* xr = x + (size_t)n*6;
  const float x0=xr[0],x1=xr[1],x2=xr[2],x3=xr[3],x4=xr[4],x5=xr[5];
  const float sq = x0*x0+x1*x1+x2*x2+x3*x3+x4*x4+x5*x5;
  PA[n] = make_float4(x0,x1,x2,x3);
  PB[n] = make_float4(x4,x5,sq,0.f);
}

// ---------------- weight conversion: W2, W3, m1_W, m2_W -> bf16 ----------------
__global__ __launch_bounds__(256) void wconv_k(const float* __restrict__ W2, const float* __restrict__ W3,
                                               const float* __restrict__ m1W, const float* __restrict__ m2W,
                                               unsigned short* __restrict__ o){
  const int i = blockIdx.x*256 + threadIdx.x;   // 122880 total
  float v;
  if (i < 65536)       v = W2[i];
  else if (i < 98304)  v = W3[i-65536];
  else if (i < 114688) v = m1W[i-98304];
  else                 v = m2W[i-114688];
  o[i] = f2bf(v);
}

// ---------------- kNN (R8 known-good): single pass, kp[32] packed keys in regs,
//                  exact lane-min pivot, compact, exact u64 bitonic finish ----------------
__global__ void knn_k(const float4* __restrict__ PA, const float4* __restrict__ PB,
                      int* __restrict__ nbr){
  __shared__ float4 A4[TS];
  __shared__ float4 B4[TS];
  __shared__ unsigned skey[4][KCAP];
  __shared__ unsigned sslot[4][KCAP];
  const int t = threadIdx.x, w = t >> 6, lane = t & 63;
  const int n = blockIdx.x*4 + w;
  const int base = n & ~(NPB-1);
  const float4 qa = PA[n];
  const float4 qb = PB[n];
  const float sqn = qb.z;
  const int selfslot = n - base;

  unsigned kp[32];
  unsigned minu = 0xFFFFFFFFu;
#pragma unroll
  for (int tile=0; tile<NPB/TS; ++tile){
    __syncthreads();   // all waves done reading previous tile
#pragma unroll
    for (int i=t; i<TS; i+=256){
      A4[i] = PA[base+tile*TS+i];
      B4[i] = PB[base+tile*TS+i];
    }
    __syncthreads();
    unsigned lo = 0;
#pragma unroll
    for (int it=0; it<TS/64; ++it){
      const int s = it*64 + lane;
      unsigned u = dkey(qa, qb, sqn, A4[s], B4[s]);
      if (tile*TS + s == selfslot) u = 0xFFFFFFFFu;   // exclude self
      minu = u < minu ? u : minu;
      if ((it & 1) == 0) lo = u >> 16;
      else               kp[(tile*(TS/64)+it)>>1] = lo | (u & 0xFFFF0000u);
    }
  }

  // pivot: 16th smallest lane-min (self excluded in-pass) >= true 16th key
  unsigned T = bsort32(minu, lane);
  T = __shfl(T, 15);
  const unsigned T16 = T >> 16;

  // compact survivors (truncated key <= T16 -> superset of true top-16)
  int cnt = 0;
#pragma unroll
  for (int q=0; q<64; ++q){
    const unsigned k16 = (kp[q>>1] >> ((q&1)*16)) & 0xFFFFu;
    const bool p = k16 <= T16;
    const unsigned long long bb = __ballot(p);
    if (p){
      const int pos = cnt + (int)__popcll(bb & ((1ull << lane) - 1ull));
      if (pos < KCAP) sslot[w][pos] = (unsigned)((q>>3)*TS + (q&7)*64 + lane);
    }
    cnt += (int)__popcll(bb);
  }
  if (cnt > KCAP) cnt = KCAP;

  // recompute exact keys for survivors (identical expression -> identical bits)
  for (int i=lane; i<cnt; i+=64){
    const int slot = (int)sslot[w][i];
    skey[w][i] = dkey(qa, qb, sqn, PA[base+slot], PB[base+slot]);
  }

  // final: exact top-16 over survivors (u64 = key||slot, ascending, slot tie-break)
  unsigned long long vbest;
  {
    unsigned long long v = ~0ull;
    if (lane < cnt) v = ((unsigned long long)skey[w][lane] << 32) | sslot[w][lane];
    vbest = bsort64(v, lane);
  }
  for (int c=1; c*64 < cnt; ++c){
    const int i = c*64 + lane;
    unsigned long long v = ~0ull;
    if (i < cnt) v = ((unsigned long long)skey[w][i] << 32) | sslot[w][i];
    v = bsort64(v, lane);
    const unsigned long long r = __shfl(v, 63-lane);
    vbest = vbest < r ? vbest : r;
#pragma unroll
    for (int j=32;j>0;j>>=1){
      const unsigned long long o = __shfl_xor(vbest, j);
      const bool keepMin = (lane & j) == 0;
      const unsigned long long mn = vbest < o ? vbest : o;
      const unsigned long long mx = vbest < o ? o : vbest;
      vbest = keepMin ? mn : mx;
    }
  }
  if (lane < 16) nbr[n*16 + lane] = base + (int)(vbest & 0xFFFFFFFFull);
}

// ---------------- layer-1 GEMM + fused attention logits (fp32) ----------------
__global__ __launch_bounds__(256) void gemm_in6(const float* __restrict__ x, const float* __restrict__ W,
                                                const float* __restrict__ asrc, const float* __restrict__ adst,
                                                float* __restrict__ h,
                                                float* __restrict__ als, float* __restrict__ ald){
  const int t = blockIdx.x*256 + threadIdx.x;  // over NN*64
  const int n = t >> 6, cg = t & 63;
  const float* xr = x + n*6;
  float xv[6];
#pragma unroll
  for (int d=0; d<6; d++) xv[d] = xr[d];
  float4 acc = make_float4(0.f,0.f,0.f,0.f);
#pragma unroll
  for (int d=0; d<6; d++){
    const float4 wv = *(const float4*)(W + d*256 + cg*4);
    acc.x += xv[d]*wv.x; acc.y += xv[d]*wv.y; acc.z += xv[d]*wv.z; acc.w += xv[d]*wv.w;
  }
  *(float4*)(h + n*256 + cg*4) = acc;

  const int head = cg >> 4;
  const float4 av = *(const float4*)(asrc + head*64 + (cg&15)*4);
  const float4 dv = *(const float4*)(adst + head*64 + (cg&15)*4);
  float s = acc.x*av.x + acc.y*av.y + acc.z*av.z + acc.w*av.w;
  float d = acc.x*dv.x + acc.y*dv.y + acc.z*dv.z + acc.w*dv.w;
#pragma unroll
  for (int off=1; off<16; off<<=1){
    s += __shfl_xor(s, off);
    d += __shfl_xor(d, off);
  }
  if ((cg & 15) == 0){
    als[n*4 + head] = s;
    ald[n*4 + head] = d;
  }
}

// ---------------- attention logits from fp32 H ----------------
template<int HEADS, int C>
__global__ __launch_bounds__(256) void al_k(const float* __restrict__ h, const float* __restrict__ asrc,
                                            const float* __restrict__ adst, float* __restrict__ als,
                                            float* __restrict__ ald){
  const int t = blockIdx.x*256 + threadIdx.x;  // over NN*HEADS
  const int n = t / HEADS, hd = t % HEADS;
  const float* hp = h + (n*HEADS + hd)*C;
  const float* ap = asrc + hd*C;
  const float* dp = adst + hd*C;
  float s=0.f, d=0.f;
#pragma unroll 4
  for (int c=0;c<C;c+=4){
    const float4 v = *(const float4*)(hp+c);
    const float4 a = *(const float4*)(ap+c);
    const float4 b = *(const float4*)(dp+c);
    s += v.x*a.x + v.y*a.y + v.z*a.z + v.w*a.w;
    d += v.x*b.x + v.y*b.y + v.z*b.z + v.w*b.w;
  }
  als[t] = s; ald[t] = d;
}

// ---------------- GAT aggregation (fp32 gather) -> bf16 output rows;
//                  RES fuses x@res_W + res_b (layer 3) ----------------
template<int HEADS, int C, bool RES>
__global__ __launch_bounds__(256) void agg_k(const float* __restrict__ h, const float* __restrict__ als,
                                             const float* __restrict__ ald, const int* __restrict__ nbr,
                                             const float* __restrict__ bias, unsigned short* __restrict__ out,
                                             const float* __restrict__ xin, const float* __restrict__ rW,
                                             const float* __restrict__ rb){
  constexpr int CT = HEADS*C;
  constexpr int F  = CT/64;
  const int w = threadIdx.x >> 6, lane = threadIdx.x & 63;
  const int n = blockIdx.x*4 + w;
  const int head = (lane*F)/C;
  const int col  = lane*F;
  const int nb = nbr[n*16 + (lane & 15)];
  const float aldn = ald[n*HEADS + head];
  float e[17];
#pragma unroll
  for (int j=0;j<17;j++){
    const int sj = (j<16) ? __shfl(nb, j) : n;
    const float v = als[sj*HEADS + head] + aldn;
    e[j] = v > 0.f ? v : 0.2f*v;
  }
  float mx = e[0];
#pragma unroll
  for (int j=1;j<17;j++) mx = fmaxf(mx, e[j]);
  float den = 0.f;
#pragma unroll
  for (int j=0;j<17;j++){ e[j] = expf(e[j]-mx); den += e[j]; }
  float acc[F];
#pragma unroll
  for (int f=0;f<F;f++) acc[f]=0.f;
#pragma unroll
  for (int j=0;j<17;j++){
    const int sj = (j<16) ? __shfl(nb, j) : n;
    const float* hp = h + sj*CT + col;
    if constexpr (F==4){
      const float4 v = *(const float4*)hp;
      acc[0] += e[j]*v.x; acc[1] += e[j]*v.y; acc[2] += e[j]*v.z; acc[3] += e[j]*v.w;
    } else {
      const float2 v = *(const float2*)hp;
      acc[0] += e[j]*v.x; acc[1] += e[j]*v.y;
    }
  }
  const float inv = 1.f/den;
  if constexpr (F==4){
    ushort4 o;
    o.x = f2bf(gelu_f(acc[0]*inv + bias[col+0]));
    o.y = f2bf(gelu_f(acc[1]*inv + bias[col+1]));
    o.z = f2bf(gelu_f(acc[2]*inv + bias[col+2]));
    o.w = f2bf(gelu_f(acc[3]*inv + bias[col+3]));
    *(ushort4*)(out + (size_t)n*CT + col) = o;
  } else {
    float v0 = gelu_f(acc[0]*inv + bias[col+0]);
    float v1 = gelu_f(acc[1]*inv + bias[col+1]);
    if constexpr (RES){
      const float* xr = xin + (size_t)n*6;
      float r0 = rb[col+0], r1 = rb[col+1];
#pragma unroll
      for (int d=0; d<6; d++){
        const float xv = xr[d];
        r0 += xv*rW[d*128 + col+0];
        r1 += xv*rW[d*128 + col+1];
      }
      v0 += r0; v1 += r1;
    }
    ushort2 o;
    o.x = f2bf(v0); o.y = f2bf(v1);
    *(ushort2*)(out + (size_t)n*CT + col) = o;
  }
}

// ---------------- bf16 MFMA GEMM: A[M,KC]bf16 @ B[KC,NC]bf16, BM=128 BN=64 BK=32,
//                  4 waves x (2x4 16x16 frags); LDS layout [k>>3][row|col][k&7] gives
//                  conflict-free ds_read_b128 fragment loads ----------------
template<int KC, int NC, bool BIAS, bool GELU, bool OUTBF16>
__global__ __launch_bounds__(256) void mgemm_k(const unsigned short* __restrict__ A,
                                               const unsigned short* __restrict__ B,
                                               const float* __restrict__ bias, void* __restrict__ Cout){
  __shared__ unsigned short As[4*128*8];   // [g][row][j]
  __shared__ unsigned short Bs[4*64*8];    // [g][n][j]
  const int t = threadIdx.x, wid = t >> 6, lane = t & 63;
  const int r0 = blockIdx.x*128, c0 = blockIdx.y*64;
  const int lg = lane >> 4, l15 = lane & 15;
  float4v acc[2][4];
#pragma unroll
  for (int rf=0;rf<2;rf++)
#pragma unroll
    for (int cf=0;cf<4;cf++)
#pragma unroll
      for (int r=0;r<4;r++) acc[rf][cf][r] = 0.f;

  const int arow = t >> 1, ak0 = (t & 1)*16;
  const int bk = t >> 3, bn0 = (t & 7)*8;

#pragma unroll 1
  for (int kc=0; kc<KC; kc+=32){
    __syncthreads();
    // A tile: 2x 16B loads per thread -> 2x b128 LDS writes
    const unsigned short* Ap = A + (size_t)(r0+arow)*KC + kc + ak0;
    const short8v av0 = *(const short8v*)Ap;
    const short8v av1 = *(const short8v*)(Ap + 8);
    *(short8v*)&As[((ak0>>3)+0)*1024 + arow*8] = av0;
    *(short8v*)&As[((ak0>>3)+1)*1024 + arow*8] = av1;
    // B tile: coalesced global row read, scattered u16 LDS writes
    const unsigned short* Bp = B + (size_t)(kc+bk)*NC + c0 + bn0;
    const short8v bv = *(const short8v*)Bp;
#pragma unroll
    for (int i=0;i<8;i++) Bs[(bk>>3)*512 + (bn0+i)*8 + (bk&7)] = (unsigned short)bv[i];
    __syncthreads();

    short8v af0 = *(const short8v*)&As[lg*1024 + (wid*32 +  0 + l15)*8];
    short8v af1 = *(const short8v*)&As[lg*1024 + (wid*32 + 16 + l15)*8];
    short8v bf[4];
#pragma unroll
    for (int c=0;c<4;c++) bf[c] = *(const short8v*)&Bs[lg*512 + (c*16 + l15)*8];
#pragma unroll
    for (int cf=0;cf<4;cf++){
      acc[0][cf] = __builtin_amdgcn_mfma_f32_16x16x32_bf16(af0, bf[cf], acc[0][cf], 0,0,0);
      acc[1][cf] = __builtin_amdgcn_mfma_f32_16x16x32_bf16(af1, bf[cf], acc[1][cf], 0,0,0);
    }
  }

  // epilogue: D[row=(lane>>4)*4+r][col=lane&15] per frag [measured: m89]
#pragma unroll
  for (int rf=0;rf<2;rf++)
#pragma unroll
    for (int cf=0;cf<4;cf++)
#pragma unroll
      for (int r=0;r<4;r++){
        const int row = r0 + wid*32 + rf*16 + lg*4 + r;
        const int col = c0 + cf*16 + l15;
        float v = acc[rf][cf][r];
        if constexpr (BIAS) v += bias[col];
        if constexpr (GELU) v = gelu_f(v);
        if constexpr (OUTBF16) ((unsigned short*)Cout)[(size_t)row*NC + col] = f2bf(v);
        else                   ((float*)Cout)[(size_t)row*NC + col] = v;
      }
}

// ---------------- final tiny GEMM: bf16 A[NN,64] @ fp32 W[64,6] + b ----------------
__global__ __launch_bounds__(256) void m3_k(const unsigned short* __restrict__ A, const float* __restrict__ W,
                                            const float* __restrict__ bias, float* __restrict__ out){
  __shared__ float Wl[64*6];
  __shared__ float bl[6];
  const int t = threadIdx.x;
  for (int i=t; i<384; i+=256) Wl[i] = W[i];
  if (t < 6) bl[t] = bias[t];
  __syncthreads();
  const int n = blockIdx.x*256 + t;
  const unsigned short* ap = A + (size_t)n*64;
  float acc[6] = {0.f,0.f,0.f,0.f,0.f,0.f};
  for (int k=0;k<64;k+=8){
    const short8v v = *(const short8v*)(ap+k);
#pragma unroll
    for (int u=0;u<8;u++){
      const float f = bf2f((unsigned short)v[u]);
#pragma unroll
      for (int j=0;j<6;j++)
        acc[j] += f*Wl[(k+u)*6+j];
    }
  }
#pragma unroll
  for (int j=0;j<6;j++) out[n*6+j] = acc[j] + bl[j];
}

extern "C" void kernel_launch(void* const* d_in, const int* in_sizes, int n_in,
                              void* d_out, int out_size, void* d_ws, size_t ws_size,
                              hipStream_t stream){
  (void)in_sizes; (void)n_in; (void)out_size; (void)ws_size;
  const float* x      = (const float*)d_in[0];
  const float* W1     = (const float*)d_in[1];
  const float* a_src1 = (const float*)d_in[2];
  const float* a_dst1 = (const float*)d_in[3];
  const float* b1     = (const float*)d_in[4];
  const float* W2     = (const float*)d_in[5];
  const float* a_src2 = (const float*)d_in[6];
  const float* a_dst2 = (const float*)d_in[7];
  const float* b2     = (const float*)d_in[8];
  const float* W3     = (const float*)d_in[9];
  const float* a_src3 = (const float*)d_in[10];
  const float* a_dst3 = (const float*)d_in[11];
  const float* b3     = (const float*)d_in[12];
  const float* res_W  = (const float*)d_in[13];
  const float* res_b  = (const float*)d_in[14];
  const float* m1_W   = (const float*)d_in[15];
  const float* m1_b   = (const float*)d_in[16];
  const float* m2_W   = (const float*)d_in[17];
  const float* m2_b   = (const float*)d_in[18];
  const float* m3_W   = (const float*)d_in[19];
  const float* m3_b   = (const float*)d_in[20];
  float* out = (float*)d_out;

  char* wsb = (char*)d_ws;
  int*            nbr = (int*)wsb;                                   // 1 MB
  float*          H   = (float*)(wsb + (1u<<20));                    // 16 MB fp32 [NN,256]
  unsigned short* Yb  = (unsigned short*)(wsb + (17u<<20));          // 8 MB bf16 [NN,256]
  unsigned short* Hb  = (unsigned short*)(wsb + (25u<<20));          // 4 MB bf16 [NN,128]
  unsigned short* Y2b = (unsigned short*)(wsb + (29u<<20));          // 2 MB bf16 [NN,64]
  float*          ALS = (float*)(wsb + (31u<<20));                   // 256 KB
  float*          ALD = ALS + NN*4;                                  // 256 KB
  float4*         PA  = (float4*)(wsb + (31u<<20) + (512u<<10));     // 256 KB
  float4*         PB  = PA + NN;                                     // 256 KB
  unsigned short* Wb  = (unsigned short*)(wsb + (32u<<20) + (512u<<10)); // 240 KB
  unsigned short* W2b = Wb;
  unsigned short* W3b = Wb + 65536;
  unsigned short* m1b = Wb + 98304;
  unsigned short* m2b = Wb + 114688;

  pack_k<<<NN/256, 256, 0, stream>>>(x, PA, PB);
  wconv_k<<<480, 256, 0, stream>>>(W2, W3, m1_W, m2_W, Wb);
  knn_k<<<NN/4, 256, 0, stream>>>(PA, PB, nbr);

  // GAT layer 1: 6 -> 4x64 (al fused into GEMM), agg -> bf16
  gemm_in6<<<NN/4, 256, 0, stream>>>(x, W1, a_src1, a_dst1, H, ALS, ALD);
  agg_k<4,64,false><<<NN/4, 256, 0, stream>>>(H, ALS, ALD, nbr, b1, Yb, nullptr, nullptr, nullptr);

  // GAT layer 2: 256 -> 4x64 (bf16 MFMA GEMM -> fp32 H)
  mgemm_k<256,256,false,false,false><<<dim3(128,4), 256, 0, stream>>>(Yb, W2b, nullptr, H);
  al_k<4,64><<<NN*4/256, 256, 0, stream>>>(H, a_src2, a_dst2, ALS, ALD);
  agg_k<4,64,false><<<NN/4, 256, 0, stream>>>(H, ALS, ALD, nbr, b2, Yb, nullptr, nullptr, nullptr);

  // GAT layer 3: 256 -> 1x128, residual fused in agg
  mgemm_k<256,128,false,false,false><<<dim3(128,2), 256, 0, stream>>>(Yb, W3b, nullptr, H);
  al_k<1,128><<<NN/256, 256, 0, stream>>>(H, a_src3, a_dst3, ALS, ALD);
  agg_k<1,128,true><<<NN/4, 256, 0, stream>>>(H, ALS, ALD, nbr, b3, Yb, x, res_W, res_b);

  // MLP: bf16 MFMA with fused bias+gelu
  mgemm_k<128,128,true,true,true><<<dim3(128,2), 256, 0, stream>>>(Yb, m1b, m1_b, Hb);
  mgemm_k<128,64,true,true,true><<<dim3(128,1), 256, 0, stream>>>(Hb, m2b, m2_b, Y2b);
  m3_k<<<NN/256, 256, 0, stream>>>(Y2b, m3_W, m3_b, out);
}